// Round 2
// baseline (973.419 us; speedup 1.0000x reference)
//
#include <hip/hip_runtime.h>

#define NPTS  4096
#define MQ    1024
#define BATCH 16
#define KNN   32
#define CIN   64
#define C0    67   // Cin + 3 (use_xyz)
#define H1D   64
#define H2D   128

// ---------------------------------------------------------------------------
// Kernel 1: exact KNN per query via radix-select on fp32 d2 bit-keys.
// d2 computed with the SAME association as the numpy reference
// ((x^2+y^2)+z^2 sums, ((qx*px+qy*py)+qz*pz) dot, (a+b)-2c), using
// non-contractible __f*_rn intrinsics so selection matches bitwise.
// ---------------------------------------------------------------------------
__global__ __launch_bounds__(256) void knn_kernel(
    const float* __restrict__ pos, const int* __restrict__ idx,
    float* __restrict__ pos_q, int* __restrict__ nn)
{
    const int bid = blockIdx.x;            // 0 .. B*M-1
    const int b   = bid >> 10;             // M = 1024
    const int m   = bid & (MQ - 1);
    const int t   = threadIdx.x;

    __shared__ unsigned int keys[NPTS];    // 16 KB
    __shared__ unsigned int hist[256];
    __shared__ unsigned int scn[256];
    __shared__ unsigned int sc[4];
    __shared__ int tiebuf[64];
    __shared__ int outidx[KNN];

    const float* pb = pos + (size_t)b * NPTS * 3;
    const int qn = idx[(size_t)b * MQ + m];   // harness delivers int64 as int32
    const float qx = pb[qn * 3 + 0], qy = pb[qn * 3 + 1], qz = pb[qn * 3 + 2];
    const float qq = __fadd_rn(__fadd_rn(__fmul_rn(qx, qx), __fmul_rn(qy, qy)),
                               __fmul_rn(qz, qz));

    for (int i = 0; i < NPTS / 256; ++i) {
        const int n = i * 256 + t;
        const float px = pb[n * 3 + 0], py = pb[n * 3 + 1], pz = pb[n * 3 + 2];
        const float pp = __fadd_rn(__fadd_rn(__fmul_rn(px, px), __fmul_rn(py, py)),
                                   __fmul_rn(pz, pz));
        const float qp = __fadd_rn(__fadd_rn(__fmul_rn(qx, px), __fmul_rn(qy, py)),
                                   __fmul_rn(qz, pz));
        const float d2 = __fsub_rn(__fadd_rn(qq, pp), __fmul_rn(2.0f, qp));
        unsigned int u = __float_as_uint(d2);
        u = (u & 0x80000000u) ? ~u : (u | 0x80000000u);   // monotone map
        keys[n] = u;
    }

    // exact radix select of the rank-(K-1) smallest key (0-indexed)
    unsigned int prefix = 0u;
    unsigned int rank   = KNN - 1;
    for (int pass = 0; pass < 4; ++pass) {
        const int shift = 24 - pass * 8;
        hist[t] = 0u;
        __syncthreads();
        for (int i = 0; i < NPTS / 256; ++i) {
            const unsigned int u = keys[i * 256 + t];
            const bool match =
                (pass == 0) || ((u >> (shift + 8)) == (prefix >> (shift + 8)));
            if (match) atomicAdd(&hist[(u >> shift) & 255u], 1u);
        }
        __syncthreads();
        const unsigned int cnt = hist[t];
        scn[t] = cnt;
        __syncthreads();
        for (int off = 1; off < 256; off <<= 1) {   // Hillis-Steele inclusive scan
            const unsigned int mine  = scn[t];
            const unsigned int other = (t >= off) ? scn[t - off] : 0u;
            __syncthreads();
            scn[t] = mine + other;
            __syncthreads();
        }
        const unsigned int incl = scn[t];
        const unsigned int excl = incl - cnt;
        if (rank >= excl && rank < incl) {
            sc[0] = prefix | ((unsigned int)t << shift);
            sc[1] = rank - excl;
        }
        __syncthreads();
        prefix = sc[0];
        rank   = sc[1];
        __syncthreads();
    }

    // collect: all keys < T, plus (rank+1) smallest-index keys == T
    const unsigned int T = prefix;
    if (t == 0) { sc[2] = 0u; sc[3] = 0u; }
    __syncthreads();
    for (int i = 0; i < NPTS / 256; ++i) {
        const int n = i * 256 + t;
        const unsigned int u = keys[n];
        if (u < T) {
            const unsigned int slot = atomicAdd(&sc[2], 1u);
            if (slot < KNN) outidx[slot] = n;
        } else if (u == T) {
            const unsigned int slot = atomicAdd(&sc[3], 1u);
            if (slot < 64u) tiebuf[slot] = n;
        }
    }
    __syncthreads();
    const int cnt_less = (int)sc[2];
    const int cnt_eq   = min((int)sc[3], 64);
    const int need     = KNN - cnt_less;
    if (t == 0 && need > 0) {
        for (int j = 0; j < need; ++j) {     // lowest-index tie-break (matches top_k)
            int best = 0x7fffffff, bi = 0;
            for (int i2 = 0; i2 < cnt_eq; ++i2)
                if (tiebuf[i2] < best) { best = tiebuf[i2]; bi = i2; }
            tiebuf[bi] = 0x7fffffff;
            outidx[cnt_less + j] = best;
        }
    }
    __syncthreads();
    if (t < KNN) nn[(size_t)bid * KNN + t] = outidx[t];
    if (t < 3)  pos_q[(size_t)bid * 3 + t] = (t == 0) ? qx : ((t == 1) ? qy : qz);
}

// ---------------------------------------------------------------------------
// Kernel 2: gather + MLP(67->64->128, ReLU) + max over K.
// One 64-thread block handles 2 queries (64 rows, 1 row/thread).
// x and h1 staged transposed in LDS -> lane-consecutive ds_reads.
// Weight loads are block-uniform -> scalar loads.
// ---------------------------------------------------------------------------
__global__ __launch_bounds__(64) void mlp_kernel(
    const float* __restrict__ pos, const float* __restrict__ feat,
    const float* __restrict__ W1, const float* __restrict__ b1,
    const float* __restrict__ W2, const float* __restrict__ b2,
    const float* __restrict__ pos_q, const int* __restrict__ nn,
    float* __restrict__ out)
{
    const int t = threadIdx.x;
    const int q = blockIdx.x * 2 + (t >> 5);   // global query id
    const int k = t & 31;
    const int b = q >> 10;

    __shared__ float xs[C0 * 64];    // 17.2 KB, xs[c*64 + row]
    __shared__ float h1s[H1D * 64];  // 16 KB,  h1s[d*64 + row]

    const int n = nn[(size_t)q * KNN + k];
    const float* pb = pos + (size_t)b * NPTS * 3;
    const float qx = pos_q[q * 3 + 0], qy = pos_q[q * 3 + 1], qz = pos_q[q * 3 + 2];
    xs[0 * 64 + t] = pb[n * 3 + 0] - qx;
    xs[1 * 64 + t] = pb[n * 3 + 1] - qy;
    xs[2 * 64 + t] = pb[n * 3 + 2] - qz;
    const float4* frow = (const float4*)(feat + ((size_t)b * NPTS + n) * CIN);
#pragma unroll
    for (int cc = 0; cc < CIN / 4; ++cc) {
        const float4 v = frow[cc];
        xs[(3 + 4 * cc + 0) * 64 + t] = v.x;
        xs[(3 + 4 * cc + 1) * 64 + t] = v.y;
        xs[(3 + 4 * cc + 2) * 64 + t] = v.z;
        xs[(3 + 4 * cc + 3) * 64 + t] = v.w;
    }
    __syncthreads();

    // MLP1: h1 = relu(x @ W1 + b1), 8 output channels per chunk
    for (int dc = 0; dc < H1D / 8; ++dc) {
        float acc[8];
#pragma unroll
        for (int j = 0; j < 8; ++j) acc[j] = b1[dc * 8 + j];
        for (int c = 0; c < C0; ++c) {
            const float xc = xs[c * 64 + t];
#pragma unroll
            for (int j = 0; j < 8; ++j)
                acc[j] = fmaf(xc, W1[c * H1D + dc * 8 + j], acc[j]);
        }
#pragma unroll
        for (int j = 0; j < 8; ++j)
            h1s[(dc * 8 + j) * 64 + t] = fmaxf(acc[j], 0.0f);
    }
    __syncthreads();

    // MLP2 + max over K (cross-lane max within each 32-lane half)
    float* oq = out + (size_t)q * H2D;
    for (int ddc = 0; ddc < H2D / 8; ++ddc) {
        float acc[8];
#pragma unroll
        for (int j = 0; j < 8; ++j) acc[j] = b2[ddc * 8 + j];
        for (int c = 0; c < H1D; ++c) {
            const float hc = h1s[c * 64 + t];
#pragma unroll
            for (int j = 0; j < 8; ++j)
                acc[j] = fmaf(hc, W2[c * H2D + ddc * 8 + j], acc[j]);
        }
#pragma unroll
        for (int j = 0; j < 8; ++j) {
            float v = fmaxf(acc[j], 0.0f);
#pragma unroll
            for (int s = 16; s >= 1; s >>= 1)
                v = fmaxf(v, __shfl_xor(v, s));
            if (k == 0) oq[ddc * 8 + j] = v;
        }
    }
}

extern "C" void kernel_launch(void* const* d_in, const int* in_sizes, int n_in,
                              void* d_out, int out_size, void* d_ws, size_t ws_size,
                              hipStream_t stream)
{
    const float* pos  = (const float*)d_in[0];
    const float* feat = (const float*)d_in[1];
    const float* W1   = (const float*)d_in[2];
    const float* b1   = (const float*)d_in[3];
    const float* W2   = (const float*)d_in[4];
    const float* b2   = (const float*)d_in[5];
    const int*   idx  = (const int*)d_in[6];   // int64 in reference -> int32 here

    float* pos_q = (float*)d_out;                          // [B*M*3]
    float* out   = (float*)d_out + (size_t)BATCH * MQ * 3; // [B*M*128]
    int*   nn    = (int*)d_ws;                             // [B*M*K] scratch

    knn_kernel<<<BATCH * MQ, 256, 0, stream>>>(pos, idx, pos_q, nn);
    mlp_kernel<<<BATCH * MQ / 2, 64, 0, stream>>>(pos, feat, W1, b1, W2, b2,
                                                  pos_q, nn, out);
}

// Round 3
// 306.999 us; speedup vs baseline: 3.1708x; 3.1708x over previous
//
#include <hip/hip_runtime.h>

#define NPTS  4096
#define MQ    1024
#define BATCH 16
#define KNN   32
#define CIN   64
#define H1D   64
#define H2D   128

typedef _Float16 half8 __attribute__((ext_vector_type(8)));
typedef float    floatx4 __attribute__((ext_vector_type(4)));

// ws layout: nn [16384*32 int = 2 MB] | W1f (6144 halves) | W2f (8192 halves)
#define WS_NN_BYTES ((size_t)BATCH * MQ * KNN * 4)
#define W1F_HALVES  (3 * 4 * 64 * 8)   // [kc:3][nt:4][lane:64][8]
#define W2F_HALVES  (2 * 8 * 64 * 8)   // [kc2:2][nt2:8][lane:64][8]

// ---------------------------------------------------------------------------
// Kernel 0: pre-pack W1 (67x64, zero-padded to 96) and W2 (64x128) into
// f16 MFMA B-fragment layout: B[k=quad*8+j][n=nt*16+col], lane=quad*16+col.
// ---------------------------------------------------------------------------
__global__ __launch_bounds__(256) void wprep_kernel(
    const float* __restrict__ W1, const float* __restrict__ W2,
    _Float16* __restrict__ wout)
{
    const int s = blockIdx.x * 256 + threadIdx.x;   // 0..1791
    if (s < 768) {                                   // W1 fragments
        const int kc = s >> 8, nt = (s >> 6) & 3, lane = s & 63;
        const int col = lane & 15, quad = lane >> 4;
        half8 ph;
#pragma unroll
        for (int j = 0; j < 8; ++j) {
            const int k = kc * 32 + quad * 8 + j;
            ph[j] = (k < 67) ? (_Float16)W1[k * H1D + nt * 16 + col] : (_Float16)0.0f;
        }
        *(half8*)(wout + (size_t)s * 8) = ph;
    } else {                                         // W2 fragments
        const int s2 = s - 768;
        const int kc2 = s2 >> 9, nt2 = (s2 >> 6) & 7, lane = s2 & 63;
        const int col = lane & 15, quad = lane >> 4;
        half8 ph;
#pragma unroll
        for (int j = 0; j < 8; ++j) {
            const int k = kc2 * 32 + quad * 8 + j;
            ph[j] = (_Float16)W2[k * H2D + nt2 * 16 + col];
        }
        *(half8*)(wout + (size_t)W1F_HALVES + (size_t)s2 * 8) = ph;
    }
}

// ---------------------------------------------------------------------------
// Kernel 1: exact KNN via radix-select on fp32 d2 bit-keys (bitwise-matching
// the numpy reference association — verified absmax 0.0 in round 2).
// Pass-0 histogram uses a ballot/match loop (bins are exponent-skewed: ~6
// unique -> one atomic per unique bin, not per element). Scans are wave-shfl.
// ---------------------------------------------------------------------------
__global__ __launch_bounds__(256) void knn_kernel(
    const float* __restrict__ pos, const int* __restrict__ idx,
    float* __restrict__ pos_q, int* __restrict__ nn)
{
    const int bid = blockIdx.x;
    const int b   = bid >> 10;
    const int m   = bid & (MQ - 1);
    const int t   = threadIdx.x;
    const int wv  = t >> 6, lane = t & 63;

    __shared__ unsigned int keys[NPTS];    // 16 KB
    __shared__ unsigned int hist[256];
    __shared__ unsigned int wsum[4];
    __shared__ unsigned int sc[4];
    __shared__ int tiebuf[64];
    __shared__ int outidx[KNN];

    const float* pb = pos + (size_t)b * NPTS * 3;
    const int qn = idx[(size_t)b * MQ + m];
    const float qx = pb[qn * 3 + 0], qy = pb[qn * 3 + 1], qz = pb[qn * 3 + 2];
    const float qq = __fadd_rn(__fadd_rn(__fmul_rn(qx, qx), __fmul_rn(qy, qy)),
                               __fmul_rn(qz, qz));

    for (int i = 0; i < NPTS / 256; ++i) {
        const int n = i * 256 + t;
        const float px = pb[n * 3 + 0], py = pb[n * 3 + 1], pz = pb[n * 3 + 2];
        const float pp = __fadd_rn(__fadd_rn(__fmul_rn(px, px), __fmul_rn(py, py)),
                                   __fmul_rn(pz, pz));
        const float qp = __fadd_rn(__fadd_rn(__fmul_rn(qx, px), __fmul_rn(qy, py)),
                                   __fmul_rn(qz, pz));
        const float d2 = __fsub_rn(__fadd_rn(qq, pp), __fmul_rn(2.0f, qp));
        unsigned int u = __float_as_uint(d2);
        u = (u & 0x80000000u) ? ~u : (u | 0x80000000u);
        keys[n] = u;
    }
    hist[t] = 0u;
    __syncthreads();

    unsigned int prefix = 0u, rank = KNN - 1;

    // ---- pass 0: match-loop histogram on top byte ----
    for (int i = 0; i < NPTS / 256; ++i) {
        const unsigned int bin = keys[i * 256 + t] >> 24;
        unsigned long long active = ~0ull;
        while (active) {
            const int src = __ffsll((unsigned long long)active) - 1;
            const unsigned int bb = __shfl(bin, src);
            const unsigned long long matched = __ballot(bin == bb);
            if (lane == src)
                atomicAdd(&hist[bb], (unsigned int)__popcll(matched & active));
            active &= ~matched;
        }
    }
    __syncthreads();

    for (int pass = 0; pass < 4; ++pass) {
        const int shift = 24 - pass * 8;
        if (pass > 0) {
            hist[t] = 0u;
            __syncthreads();
            for (int i = 0; i < NPTS / 256; ++i) {
                const unsigned int u = keys[i * 256 + t];
                if ((u >> (shift + 8)) == (prefix >> (shift + 8)))
                    atomicAdd(&hist[(u >> shift) & 255u], 1u);
            }
            __syncthreads();
        }
        // wave-shfl inclusive scan over 256 bins (bin = t)
        const unsigned int cntb = hist[t];
        unsigned int v = cntb;
#pragma unroll
        for (int off = 1; off < 64; off <<= 1) {
            const unsigned int o = __shfl_up(v, off);
            if (lane >= off) v += o;
        }
        if (lane == 63) wsum[wv] = v;
        __syncthreads();
        unsigned int woff = 0;
        for (int i = 0; i < wv; ++i) woff += wsum[i];
        const unsigned int incl = woff + v, excl = incl - cntb;
        if (rank >= excl && rank < incl) {
            sc[0] = prefix | ((unsigned int)t << shift);
            sc[1] = rank - excl;
        }
        __syncthreads();
        prefix = sc[0];
        rank   = sc[1];
        __syncthreads();
    }

    // ---- collect ----
    const unsigned int T = prefix;
    if (t == 0) { sc[2] = 0u; sc[3] = 0u; }
    __syncthreads();
    for (int i = 0; i < NPTS / 256; ++i) {
        const int n = i * 256 + t;
        const unsigned int u = keys[n];
        if (u < T) {
            const unsigned int slot = atomicAdd(&sc[2], 1u);
            if (slot < KNN) outidx[slot] = n;
        } else if (u == T) {
            const unsigned int slot = atomicAdd(&sc[3], 1u);
            if (slot < 64u) tiebuf[slot] = n;
        }
    }
    __syncthreads();
    const int cnt_less = (int)sc[2];
    const int cnt_eq   = min((int)sc[3], 64);
    const int need     = KNN - cnt_less;
    if (t == 0 && need > 0) {
        for (int j = 0; j < need; ++j) {
            int best = 0x7fffffff, bi = 0;
            for (int i2 = 0; i2 < cnt_eq; ++i2)
                if (tiebuf[i2] < best) { best = tiebuf[i2]; bi = i2; }
            tiebuf[bi] = 0x7fffffff;
            outidx[cnt_less + j] = best;
        }
    }
    __syncthreads();
    if (t < KNN) nn[(size_t)bid * KNN + t] = outidx[t];
    if (t < 3)  pos_q[(size_t)bid * 3 + t] = (t == 0) ? qx : ((t == 1) ? qy : qz);
}

// ---------------------------------------------------------------------------
// Kernel 2: fused gather + MLP via f16 MFMA 16x16x32 + max over K.
// Block = 256 thr = 4 waves = 4 queries (wave-private after one barrier).
// LDS: W1f 12K | W2f 16K | per-wave 6K region (X-frags, reused for H1-frags
// after A-fragments are hoisted to VGPRs). 52 KB -> 3 blocks/CU.
// ---------------------------------------------------------------------------
#define W1F_H 0
#define W2F_H 6144
#define XH_H  14336
#define SH_HALVES (XH_H + 4 * 3072)   // 26624 halves = 52 KB

__global__ __launch_bounds__(256) void mlp_kernel(
    const float* __restrict__ pos, const float* __restrict__ feat,
    const float* __restrict__ b1, const float* __restrict__ b2,
    const float* __restrict__ pos_q, const int* __restrict__ nn,
    const _Float16* __restrict__ wf, float* __restrict__ out)
{
    __shared__ _Float16 sh[SH_HALVES];
    const int t = threadIdx.x;
    const int w = t >> 6, lane = t & 63;
    const int col = lane & 15, quad = lane >> 4;
    const int qblk = blockIdx.x * 4;

    // 1. weights -> LDS (linear copy, fragment layout already in ws)
    {
        const int4* src = (const int4*)wf;
        int4* dst = (int4*)sh;
#pragma unroll
        for (int r = 0; r < 7; ++r) dst[t + 256 * r] = src[t + 256 * r];
    }

    // 2. gather + pack X A-fragments (wave w fills its own query's region)
    {
        const int r = t >> 1, h = t & 1;
        const int ql = r >> 5, kk = r & 31;
        const int q = qblk + ql, b = q >> 10;
        const int n = nn[(size_t)q * KNN + kk];
        const float* frow = feat + ((size_t)(b * NPTS + n)) * CIN;
        const float4* f4 = (const float4*)frow;
        const int mt = kk >> 4, lrow = kk & 15;
        const int base = XH_H + ql * 3072;
        if (h == 0) {                       // cols 0..47: rel(3) + feat[0..44]
            float rel[3];
#pragma unroll
            for (int c = 0; c < 3; ++c)
                rel[c] = pos[(size_t)b * NPTS * 3 + n * 3 + c] - pos_q[(size_t)q * 3 + c];
            float fb[48];
#pragma unroll
            for (int ii = 0; ii < 12; ++ii) {
                const float4 v = f4[ii];
                fb[4*ii] = v.x; fb[4*ii+1] = v.y; fb[4*ii+2] = v.z; fb[4*ii+3] = v.w;
            }
#pragma unroll
            for (int cidx = 0; cidx < 6; ++cidx) {
                half8 ph;
#pragma unroll
                for (int jj = 0; jj < 8; ++jj) {
                    const int c = cidx * 8 + jj;
                    ph[jj] = (_Float16)((c < 3) ? rel[c] : fb[c - 3]);
                }
                const int kc = cidx >> 2, qd = cidx & 3;
                *(half8*)&sh[base + ((kc * 2 + mt) * 64 + qd * 16 + lrow) * 8] = ph;
            }
        } else {                            // cols 48..95: feat[45..63] + pad
            float fb[20];                    // feat cols 44..63
#pragma unroll
            for (int ii = 0; ii < 5; ++ii) {
                const float4 v = f4[11 + ii];
                fb[4*ii] = v.x; fb[4*ii+1] = v.y; fb[4*ii+2] = v.z; fb[4*ii+3] = v.w;
            }
#pragma unroll
            for (int cidx = 6; cidx < 12; ++cidx) {
                half8 ph;
#pragma unroll
                for (int jj = 0; jj < 8; ++jj) {
                    const int c = cidx * 8 + jj;
                    ph[jj] = (_Float16)((c < 67) ? fb[c - 47] : 0.0f);
                }
                const int kc = cidx >> 2, qd = cidx & 3;
                *(half8*)&sh[base + ((kc * 2 + mt) * 64 + qd * 16 + lrow) * 8] = ph;
            }
        }
    }
    __syncthreads();   // weights (cross-wave) + X-frags ready

    const int q = qblk + w;
    const int wbase = XH_H + w * 3072;

    // 3. layer 1: hoist A-frags, then per-nt MFMA; epilogue packs H1 A-frags
    half8 af[3][2];
#pragma unroll
    for (int kc = 0; kc < 3; ++kc)
#pragma unroll
        for (int mt = 0; mt < 2; ++mt)
            af[kc][mt] = *(const half8*)&sh[wbase + ((kc * 2 + mt) * 64 + lane) * 8];

#pragma unroll
    for (int nt = 0; nt < 4; ++nt) {
        const float bv = b1[nt * 16 + col];
        floatx4 acc0 = {bv, bv, bv, bv}, acc1 = acc0;
#pragma unroll
        for (int kc = 0; kc < 3; ++kc) {
            const half8 bf = *(const half8*)&sh[W1F_H + ((kc * 4 + nt) * 64 + lane) * 8];
            acc0 = __builtin_amdgcn_mfma_f32_16x16x32_f16(af[kc][0], bf, acc0, 0, 0, 0);
            acc1 = __builtin_amdgcn_mfma_f32_16x16x32_f16(af[kc][1], bf, acc1, 0, 0, 0);
        }
        const int kc2 = nt >> 1;
        const int quad2 = (((nt & 1) * 16) + col) >> 3;
        const int j2 = col & 7;
#pragma unroll
        for (int mt = 0; mt < 2; ++mt) {
            const floatx4 a = mt ? acc1 : acc0;
#pragma unroll
            for (int reg = 0; reg < 4; ++reg) {
                const int row = quad * 4 + reg;     // C-layout: row=(lane>>4)*4+reg
                sh[wbase + ((kc2 * 2 + mt) * 64 + quad2 * 16 + row) * 8 + j2] =
                    (_Float16)fmaxf(a[reg], 0.0f);
            }
        }
    }

    // 4. layer 2 + max over K (wave-private: no barrier needed)
    half8 a2[2][2];
#pragma unroll
    for (int kc2 = 0; kc2 < 2; ++kc2)
#pragma unroll
        for (int mt = 0; mt < 2; ++mt)
            a2[kc2][mt] = *(const half8*)&sh[wbase + ((kc2 * 2 + mt) * 64 + lane) * 8];

    float* oq = out + (size_t)q * H2D;
#pragma unroll
    for (int nt2 = 0; nt2 < 8; ++nt2) {
        const float bv = b2[nt2 * 16 + col];
        floatx4 acc0 = {bv, bv, bv, bv}, acc1 = acc0;
#pragma unroll
        for (int kc2 = 0; kc2 < 2; ++kc2) {
            const half8 bf = *(const half8*)&sh[W2F_H + ((kc2 * 8 + nt2) * 64 + lane) * 8];
            acc0 = __builtin_amdgcn_mfma_f32_16x16x32_f16(a2[kc2][0], bf, acc0, 0, 0, 0);
            acc1 = __builtin_amdgcn_mfma_f32_16x16x32_f16(a2[kc2][1], bf, acc1, 0, 0, 0);
        }
        float mm = fmaxf(fmaxf(fmaxf(acc0[0], acc0[1]), fmaxf(acc0[2], acc0[3])),
                         fmaxf(fmaxf(acc1[0], acc1[1]), fmaxf(acc1[2], acc1[3])));
        mm = fmaxf(mm, 0.0f);                       // relu before max (all >=0)
        mm = fmaxf(mm, __shfl_xor(mm, 16));
        mm = fmaxf(mm, __shfl_xor(mm, 32));
        if (lane < 16) oq[nt2 * 16 + lane] = mm;
    }
}

extern "C" void kernel_launch(void* const* d_in, const int* in_sizes, int n_in,
                              void* d_out, int out_size, void* d_ws, size_t ws_size,
                              hipStream_t stream)
{
    const float* pos  = (const float*)d_in[0];
    const float* feat = (const float*)d_in[1];
    const float* W1   = (const float*)d_in[2];
    const float* b1   = (const float*)d_in[3];
    const float* W2   = (const float*)d_in[4];
    const float* b2   = (const float*)d_in[5];
    const int*   idx  = (const int*)d_in[6];   // int64 delivered as int32

    float* pos_q = (float*)d_out;                          // [B*M*3]
    float* out   = (float*)d_out + (size_t)BATCH * MQ * 3; // [B*M*128]
    int*   nn    = (int*)d_ws;
    _Float16* wf = (_Float16*)((char*)d_ws + WS_NN_BYTES);

    wprep_kernel<<<7, 256, 0, stream>>>(W1, W2, wf);
    knn_kernel<<<BATCH * MQ, 256, 0, stream>>>(pos, idx, pos_q, nn);
    mlp_kernel<<<BATCH * MQ / 4, 256, 0, stream>>>(pos, feat, b1, b2,
                                                   pos_q, nn, wf, out);
}

// Round 4
// 229.758 us; speedup vs baseline: 4.2367x; 1.3362x over previous
//
#include <hip/hip_runtime.h>

#define NPTS  4096
#define MQ    1024
#define BATCH 16
#define KNN   32
#define CIN   64
#define H1D   64
#define H2D   128

typedef _Float16 half8 __attribute__((ext_vector_type(8)));
typedef float    floatx4 __attribute__((ext_vector_type(4)));

// ws layout: nn [2 MB] | W1f+W2f fragments [28 KB] | pp [256 KB]
#define WS_NN_BYTES ((size_t)BATCH * MQ * KNN * 4)
#define W1F_HALVES  (3 * 4 * 64 * 8)
#define W2F_HALVES  (2 * 8 * 64 * 8)
#define WS_PP_OFF   (WS_NN_BYTES + (W1F_HALVES + W2F_HALVES) * 2)

// ---------------------------------------------------------------------------
// Kernel 0: pack W1/W2 into f16 MFMA B-fragment layout  +  precompute |p|^2
// (pp uses the exact reference association (x^2+y^2)+z^2 with rn intrinsics).
// ---------------------------------------------------------------------------
__global__ __launch_bounds__(256) void wprep_kernel(
    const float* __restrict__ W1, const float* __restrict__ W2,
    const float* __restrict__ pos,
    _Float16* __restrict__ wout, float* __restrict__ pp)
{
    const int gid = blockIdx.x * 256 + threadIdx.x;
    if (gid < 768) {                                 // W1 fragments
        const int s = gid;
        const int kc = s >> 8, nt = (s >> 6) & 3, lane = s & 63;
        const int col = lane & 15, quad = lane >> 4;
        half8 ph;
#pragma unroll
        for (int j = 0; j < 8; ++j) {
            const int k = kc * 32 + quad * 8 + j;
            ph[j] = (k < 67) ? (_Float16)W1[k * H1D + nt * 16 + col] : (_Float16)0.0f;
        }
        *(half8*)(wout + (size_t)s * 8) = ph;
    } else if (gid < 1792) {                         // W2 fragments
        const int s2 = gid - 768;
        const int kc2 = s2 >> 9, nt2 = (s2 >> 6) & 7, lane = s2 & 63;
        const int col = lane & 15, quad = lane >> 4;
        half8 ph;
#pragma unroll
        for (int j = 0; j < 8; ++j) {
            const int k = kc2 * 32 + quad * 8 + j;
            ph[j] = (_Float16)W2[k * H2D + nt2 * 16 + col];
        }
        *(half8*)(wout + (size_t)W1F_HALVES + (size_t)s2 * 8) = ph;
    } else {                                         // pp for all B*N points
        const int p = gid - 1792;
        if (p < BATCH * NPTS) {
            const float px = pos[p * 3 + 0], py = pos[p * 3 + 1], pz = pos[p * 3 + 2];
            pp[p] = __fadd_rn(__fadd_rn(__fmul_rn(px, px), __fmul_rn(py, py)),
                              __fmul_rn(pz, pz));
        }
    }
}

// ---------------------------------------------------------------------------
// Kernel 1: exact KNN. d2 bit-keys (bitwise-matching numpy reference,
// verified absmax 0.0 in r2/r3). Select: one 11-bit 2048-bin histogram level
// (threshold bin spans only a 1.25x d2 range -> expected ~13 candidates),
// compact definite members + candidates, finish with a single-wave
// lexicographic (key,idx) rank — exact top_k tie semantics. Rare fat bins
// (m>64) fall through to further 11/10-bit levels before compacting.
// ---------------------------------------------------------------------------
__global__ __launch_bounds__(256) void knn_kernel(
    const float* __restrict__ pos, const float* __restrict__ pp,
    const int* __restrict__ idx,
    float* __restrict__ pos_q, int* __restrict__ nn)
{
    const int bid = blockIdx.x;
    const int b   = bid >> 10;
    const int m   = bid & (MQ - 1);
    const int t   = threadIdx.x;
    const int wv  = t >> 6, lane = t & 63;

    __shared__ unsigned int keys[NPTS];     // 16 KB
    __shared__ unsigned int hist[2048];     // 8 KB
    __shared__ unsigned int wsum[4];
    __shared__ unsigned int sc[8];          // 0:prefix 1:rank 2:bincnt 3:def 4:cand
    __shared__ unsigned int ckey[64];
    __shared__ int          cidx[64];
    __shared__ int          outidx[KNN];

    const float* pb  = pos + (size_t)b * NPTS * 3;
    const float* ppb = pp + (size_t)b * NPTS;
    const int qn = idx[(size_t)b * MQ + m];
    const float qx = pb[qn * 3 + 0], qy = pb[qn * 3 + 1], qz = pb[qn * 3 + 2];
    const float qq = ppb[qn];

    for (int i = 0; i < NPTS / 256; ++i) {
        const int n = i * 256 + t;
        const float px = pb[n * 3 + 0], py = pb[n * 3 + 1], pz = pb[n * 3 + 2];
        const float qp = __fadd_rn(__fadd_rn(__fmul_rn(qx, px), __fmul_rn(qy, py)),
                                   __fmul_rn(qz, pz));
        const float d2 = __fsub_rn(__fadd_rn(qq, ppb[n]), __fmul_rn(2.0f, qp));
        unsigned int u = __float_as_uint(d2);
        u = (u & 0x80000000u) ? ~u : (u | 0x80000000u);
        keys[n] = u;
    }

    unsigned int prefix = 0u, rank = KNN - 1;
    int shift = 21, bcnt = NPTS;
    for (int level = 0; level < 3; ++level) {
        shift = (level == 0) ? 21 : (level == 1) ? 10 : 0;
        const int nb = (level < 2) ? 11 : 10;
        const int nbins = 1 << nb;
        const unsigned int mask = nbins - 1;
        const int hs = shift + nb;          // 32 at level 0 (filter skipped)
        for (int j = t; j < nbins; j += 256) hist[j] = 0u;
        __syncthreads();
        for (int i = 0; i < NPTS / 256; ++i) {
            const unsigned int u = keys[i * 256 + t];
            if (level == 0 || (u >> hs) == prefix)
                atomicAdd(&hist[(u >> shift) & mask], 1u);
        }
        __syncthreads();
        // locate threshold bin: thread t owns bins [t*g, t*g+g)
        const int g = nbins >> 8;
        unsigned int s = 0;
        for (int j = 0; j < g; ++j) s += hist[t * g + j];
        unsigned int v = s;
#pragma unroll
        for (int off = 1; off < 64; off <<= 1) {
            const unsigned int o = __shfl_up(v, off);
            if (lane >= off) v += o;
        }
        if (lane == 63) wsum[wv] = v;
        __syncthreads();
        unsigned int woff = 0;
        for (int i = 0; i < wv; ++i) woff += wsum[i];
        const unsigned int incl = woff + v, excl = incl - s;
        if (s > 0 && rank >= excl && rank < incl) {
            unsigned int e = excl;
            for (int j = 0; j < g; ++j) {
                const unsigned int c = hist[t * g + j];
                if (rank < e + c) {
                    sc[0] = (prefix << nb) | (unsigned int)(t * g + j);
                    sc[1] = rank - e;
                    sc[2] = c;
                    break;
                }
                e += c;
            }
        }
        __syncthreads();
        prefix = sc[0];
        rank   = sc[1];
        bcnt   = (int)sc[2];
        __syncthreads();
        if (bcnt <= 64) break;
    }

    // compact: definite members (high bits < prefix) + candidates (== prefix)
    if (t == 0) { sc[3] = 0u; sc[4] = 0u; }
    __syncthreads();
    for (int i = 0; i < NPTS / 256; ++i) {
        const int n = i * 256 + t;
        const unsigned int u = keys[n];
        const unsigned int hp = (shift == 0) ? u : (u >> shift);
        if (hp < prefix) {
            outidx[atomicAdd(&sc[3], 1u)] = n;          // <= 31 of these
        } else if (hp == prefix) {
            const unsigned int slot = atomicAdd(&sc[4], 1u);
            if (slot < 64u) { ckey[slot] = u; cidx[slot] = n; }
        }
    }
    __syncthreads();
    const int defcnt  = (int)sc[3];
    const int candcnt = min((int)sc[4], 64);

    // wave 0: exact (key, idx) lexicographic rank among candidates
    if (wv == 0) {
        const unsigned int k_l = (lane < candcnt) ? ckey[lane] : 0xFFFFFFFFu;
        const int          i_l = (lane < candcnt) ? cidx[lane] : 0x7FFFFFFF;
        int rk = 0;
        for (int j = 0; j < candcnt; ++j) {
            const unsigned int kj = __shfl(k_l, j);
            const int          ij = __shfl(i_l, j);
            if (kj < k_l || (kj == k_l && ij < i_l)) ++rk;
        }
        if (lane < candcnt && rk <= (int)rank) outidx[defcnt + rk] = i_l;
    }
    __syncthreads();
    if (t < KNN) nn[(size_t)bid * KNN + t] = outidx[t];
    if (t < 3)  pos_q[(size_t)bid * 3 + t] = (t == 0) ? qx : ((t == 1) ? qy : qz);
}

// ---------------------------------------------------------------------------
// Kernel 2: fused gather + MLP via f16 MFMA 16x16x32 + max over K.
// (unchanged from round 3 — passed with absmax 0.031)
// ---------------------------------------------------------------------------
#define W1F_H 0
#define W2F_H 6144
#define XH_H  14336
#define SH_HALVES (XH_H + 4 * 3072)

__global__ __launch_bounds__(256) void mlp_kernel(
    const float* __restrict__ pos, const float* __restrict__ feat,
    const float* __restrict__ b1, const float* __restrict__ b2,
    const float* __restrict__ pos_q, const int* __restrict__ nn,
    const _Float16* __restrict__ wf, float* __restrict__ out)
{
    __shared__ _Float16 sh[SH_HALVES];
    const int t = threadIdx.x;
    const int w = t >> 6, lane = t & 63;
    const int col = lane & 15, quad = lane >> 4;
    const int qblk = blockIdx.x * 4;

    {
        const int4* src = (const int4*)wf;
        int4* dst = (int4*)sh;
#pragma unroll
        for (int r = 0; r < 7; ++r) dst[t + 256 * r] = src[t + 256 * r];
    }

    {
        const int r = t >> 1, h = t & 1;
        const int ql = r >> 5, kk = r & 31;
        const int q = qblk + ql, b = q >> 10;
        const int n = nn[(size_t)q * KNN + kk];
        const float* frow = feat + ((size_t)(b * NPTS + n)) * CIN;
        const float4* f4 = (const float4*)frow;
        const int mt = kk >> 4, lrow = kk & 15;
        const int base = XH_H + ql * 3072;
        if (h == 0) {
            float rel[3];
#pragma unroll
            for (int c = 0; c < 3; ++c)
                rel[c] = pos[(size_t)b * NPTS * 3 + n * 3 + c] - pos_q[(size_t)q * 3 + c];
            float fb[48];
#pragma unroll
            for (int ii = 0; ii < 12; ++ii) {
                const float4 v = f4[ii];
                fb[4*ii] = v.x; fb[4*ii+1] = v.y; fb[4*ii+2] = v.z; fb[4*ii+3] = v.w;
            }
#pragma unroll
            for (int cidx2 = 0; cidx2 < 6; ++cidx2) {
                half8 ph;
#pragma unroll
                for (int jj = 0; jj < 8; ++jj) {
                    const int c = cidx2 * 8 + jj;
                    ph[jj] = (_Float16)((c < 3) ? rel[c] : fb[c - 3]);
                }
                const int kc = cidx2 >> 2, qd = cidx2 & 3;
                *(half8*)&sh[base + ((kc * 2 + mt) * 64 + qd * 16 + lrow) * 8] = ph;
            }
        } else {
            float fb[20];
#pragma unroll
            for (int ii = 0; ii < 5; ++ii) {
                const float4 v = f4[11 + ii];
                fb[4*ii] = v.x; fb[4*ii+1] = v.y; fb[4*ii+2] = v.z; fb[4*ii+3] = v.w;
            }
#pragma unroll
            for (int cidx2 = 6; cidx2 < 12; ++cidx2) {
                half8 ph;
#pragma unroll
                for (int jj = 0; jj < 8; ++jj) {
                    const int c = cidx2 * 8 + jj;
                    ph[jj] = (_Float16)((c < 67) ? fb[c - 47] : 0.0f);
                }
                const int kc = cidx2 >> 2, qd = cidx2 & 3;
                *(half8*)&sh[base + ((kc * 2 + mt) * 64 + qd * 16 + lrow) * 8] = ph;
            }
        }
    }
    __syncthreads();

    const int q = qblk + w;
    const int wbase = XH_H + w * 3072;

    half8 af[3][2];
#pragma unroll
    for (int kc = 0; kc < 3; ++kc)
#pragma unroll
        for (int mt = 0; mt < 2; ++mt)
            af[kc][mt] = *(const half8*)&sh[wbase + ((kc * 2 + mt) * 64 + lane) * 8];

#pragma unroll
    for (int nt = 0; nt < 4; ++nt) {
        const float bv = b1[nt * 16 + col];
        floatx4 acc0 = {bv, bv, bv, bv}, acc1 = acc0;
#pragma unroll
        for (int kc = 0; kc < 3; ++kc) {
            const half8 bf = *(const half8*)&sh[W1F_H + ((kc * 4 + nt) * 64 + lane) * 8];
            acc0 = __builtin_amdgcn_mfma_f32_16x16x32_f16(af[kc][0], bf, acc0, 0, 0, 0);
            acc1 = __builtin_amdgcn_mfma_f32_16x16x32_f16(af[kc][1], bf, acc1, 0, 0, 0);
        }
        const int kc2 = nt >> 1;
        const int quad2 = (((nt & 1) * 16) + col) >> 3;
        const int j2 = col & 7;
#pragma unroll
        for (int mt = 0; mt < 2; ++mt) {
            const floatx4 a = mt ? acc1 : acc0;
#pragma unroll
            for (int reg = 0; reg < 4; ++reg) {
                const int row = quad * 4 + reg;
                sh[wbase + ((kc2 * 2 + mt) * 64 + quad2 * 16 + row) * 8 + j2] =
                    (_Float16)fmaxf(a[reg], 0.0f);
            }
        }
    }

    half8 a2[2][2];
#pragma unroll
    for (int kc2 = 0; kc2 < 2; ++kc2)
#pragma unroll
        for (int mt = 0; mt < 2; ++mt)
            a2[kc2][mt] = *(const half8*)&sh[wbase + ((kc2 * 2 + mt) * 64 + lane) * 8];

    float* oq = out + (size_t)q * H2D;
#pragma unroll
    for (int nt2 = 0; nt2 < 8; ++nt2) {
        const float bv = b2[nt2 * 16 + col];
        floatx4 acc0 = {bv, bv, bv, bv}, acc1 = acc0;
#pragma unroll
        for (int kc2 = 0; kc2 < 2; ++kc2) {
            const half8 bf = *(const half8*)&sh[W2F_H + ((kc2 * 8 + nt2) * 64 + lane) * 8];
            acc0 = __builtin_amdgcn_mfma_f32_16x16x32_f16(a2[kc2][0], bf, acc0, 0, 0, 0);
            acc1 = __builtin_amdgcn_mfma_f32_16x16x32_f16(a2[kc2][1], bf, acc1, 0, 0, 0);
        }
        float mm = fmaxf(fmaxf(fmaxf(acc0[0], acc0[1]), fmaxf(acc0[2], acc0[3])),
                         fmaxf(fmaxf(acc1[0], acc1[1]), fmaxf(acc1[2], acc1[3])));
        mm = fmaxf(mm, 0.0f);
        mm = fmaxf(mm, __shfl_xor(mm, 16));
        mm = fmaxf(mm, __shfl_xor(mm, 32));
        if (lane < 16) oq[nt2 * 16 + lane] = mm;
    }
}

extern "C" void kernel_launch(void* const* d_in, const int* in_sizes, int n_in,
                              void* d_out, int out_size, void* d_ws, size_t ws_size,
                              hipStream_t stream)
{
    const float* pos  = (const float*)d_in[0];
    const float* feat = (const float*)d_in[1];
    const float* W1   = (const float*)d_in[2];
    const float* b1   = (const float*)d_in[3];
    const float* W2   = (const float*)d_in[4];
    const float* b2   = (const float*)d_in[5];
    const int*   idx  = (const int*)d_in[6];   // int64 delivered as int32

    float* pos_q = (float*)d_out;
    float* out   = (float*)d_out + (size_t)BATCH * MQ * 3;
    int*      nn = (int*)d_ws;
    _Float16* wf = (_Float16*)((char*)d_ws + WS_NN_BYTES);
    float*    pp = (float*)((char*)d_ws + WS_PP_OFF);

    wprep_kernel<<<(1792 + BATCH * NPTS + 255) / 256, 256, 0, stream>>>(W1, W2, pos, wf, pp);
    knn_kernel<<<BATCH * MQ, 256, 0, stream>>>(pos, pp, idx, pos_q, nn);
    mlp_kernel<<<BATCH * MQ / 4, 256, 0, stream>>>(pos, feat, b1, b2,
                                                   pos_q, nn, wf, out);
}

// Round 5
// 204.873 us; speedup vs baseline: 4.7513x; 1.1215x over previous
//
#include <hip/hip_runtime.h>

#define NPTS  4096
#define MQ    1024
#define BATCH 16
#define KNN   32
#define CIN   64
#define H1D   64
#define H2D   128

typedef _Float16 half8 __attribute__((ext_vector_type(8)));
typedef float    floatx4 __attribute__((ext_vector_type(4)));

// ws layout: nn [2 MB] | W1f+W2f fragments [28 KB] | pos4 [1 MB]
#define WS_NN_BYTES ((size_t)BATCH * MQ * KNN * 4)
#define W1F_HALVES  (3 * 4 * 64 * 8)
#define W2F_HALVES  (2 * 8 * 64 * 8)
#define WS_P4_OFF   (WS_NN_BYTES + (W1F_HALVES + W2F_HALVES) * 2)

// ---------------------------------------------------------------------------
// Kernel 0: pack W1/W2 into f16 MFMA B-fragment layout + pack pos into
// float4 {x,y,z,|p|^2}  (|p|^2 with the exact reference association).
// ---------------------------------------------------------------------------
__global__ __launch_bounds__(256) void wprep_kernel(
    const float* __restrict__ W1, const float* __restrict__ W2,
    const float* __restrict__ pos,
    _Float16* __restrict__ wout, float4* __restrict__ pos4)
{
    const int gid = blockIdx.x * 256 + threadIdx.x;
    if (gid < 768) {                                 // W1 fragments
        const int s = gid;
        const int kc = s >> 8, nt = (s >> 6) & 3, lane = s & 63;
        const int col = lane & 15, quad = lane >> 4;
        half8 ph;
#pragma unroll
        for (int j = 0; j < 8; ++j) {
            const int k = kc * 32 + quad * 8 + j;
            ph[j] = (k < 67) ? (_Float16)W1[k * H1D + nt * 16 + col] : (_Float16)0.0f;
        }
        *(half8*)(wout + (size_t)s * 8) = ph;
    } else if (gid < 1792) {                         // W2 fragments
        const int s2 = gid - 768;
        const int kc2 = s2 >> 9, nt2 = (s2 >> 6) & 7, lane = s2 & 63;
        const int col = lane & 15, quad = lane >> 4;
        half8 ph;
#pragma unroll
        for (int j = 0; j < 8; ++j) {
            const int k = kc2 * 32 + quad * 8 + j;
            ph[j] = (_Float16)W2[k * H2D + nt2 * 16 + col];
        }
        *(half8*)(wout + (size_t)W1F_HALVES + (size_t)s2 * 8) = ph;
    } else {                                         // pos4 for all B*N points
        const int p = gid - 1792;
        if (p < BATCH * NPTS) {
            const float px = pos[p * 3 + 0], py = pos[p * 3 + 1], pz = pos[p * 3 + 2];
            float4 v;
            v.x = px; v.y = py; v.z = pz;
            v.w = __fadd_rn(__fadd_rn(__fmul_rn(px, px), __fmul_rn(py, py)),
                            __fmul_rn(pz, pz));
            pos4[p] = v;
        }
    }
}

// ---------------------------------------------------------------------------
// Kernel 1: exact KNN. Keys (monotone-mapped fp32 d2, bitwise-matching the
// numpy reference — verified absmax 0.0 in r2) held in 16 VGPRs/thread.
// One fused distance+histogram pass (2048 bins, 11 bits), multi-level
// fallback for fat bins rescans registers. Compact + single-wave
// lexicographic (key,idx) rank for exact top_k tie semantics.
// ---------------------------------------------------------------------------
__global__ __launch_bounds__(256, 4) void knn_kernel(
    const float4* __restrict__ pos4, const int* __restrict__ idx,
    float* __restrict__ pos_q, int* __restrict__ nn)
{
    const int bid = blockIdx.x;
    const int b   = bid >> 10;
    const int m   = bid & (MQ - 1);
    const int t   = threadIdx.x;
    const int wv  = t >> 6, lane = t & 63;

    __shared__ unsigned int hist[2048];     // 8 KB
    __shared__ unsigned int wsum[4];
    __shared__ unsigned int sc[8];          // 0:prefix 1:rank 2:bincnt 3:def 4:cand
    __shared__ unsigned int ckey[64];
    __shared__ int          cidx[64];
    __shared__ int          outidx[KNN];

    const float4* pb4 = pos4 + (size_t)b * NPTS;
    const int qn = idx[(size_t)b * MQ + m];
    const float4 qv = pb4[qn];
    const float qq = qv.w;

#pragma unroll
    for (int j = 0; j < 8; ++j) hist[t + 256 * j] = 0u;
    __syncthreads();

    // fused distance + level-0 histogram; keys stay in registers
    unsigned int k[16];
#pragma unroll
    for (int i = 0; i < 16; ++i) {
        const float4 p = pb4[i * 256 + t];
        const float qp = __fadd_rn(__fadd_rn(__fmul_rn(qv.x, p.x), __fmul_rn(qv.y, p.y)),
                                   __fmul_rn(qv.z, p.z));
        const float d2 = __fsub_rn(__fadd_rn(qq, p.w), __fmul_rn(2.0f, qp));
        unsigned int u = __float_as_uint(d2);
        u = (u & 0x80000000u) ? ~u : (u | 0x80000000u);
        k[i] = u;
        atomicAdd(&hist[u >> 21], 1u);
    }
    __syncthreads();

    unsigned int prefix = 0u, rank = KNN - 1;
    int shift = 21, bcnt;
    for (int level = 0; level < 3; ++level) {
        const int nb = (level < 2) ? 11 : 10;
        const int g  = (1 << nb) >> 8;           // bins per thread: 8 or 4
        unsigned int cnt[8];
        unsigned int s = 0;
        for (int j = 0; j < g; ++j) { cnt[j] = hist[t * g + j]; s += cnt[j]; }
        unsigned int v = s;
#pragma unroll
        for (int off = 1; off < 64; off <<= 1) {
            const unsigned int o = __shfl_up(v, off);
            if (lane >= off) v += o;
        }
        if (lane == 63) wsum[wv] = v;
        __syncthreads();
        unsigned int woff = 0;
        for (int i = 0; i < wv; ++i) woff += wsum[i];
        const unsigned int incl = woff + v, excl = incl - s;
        if (rank >= excl && rank < incl) {
            unsigned int e = excl;
            for (int j = 0; j < g; ++j) {
                if (rank < e + cnt[j]) {
                    sc[0] = (prefix << nb) | (unsigned int)(t * g + j);
                    sc[1] = rank - e;
                    sc[2] = cnt[j];
                    break;
                }
                e += cnt[j];
            }
        }
        __syncthreads();
        prefix = sc[0];
        rank   = sc[1];
        bcnt   = (int)sc[2];
        if (level == 2 || bcnt <= 64) break;

        // build next-level histogram from register keys (filtered)
        const int nshift = (level == 0) ? 10 : 0;
        const int nnb    = (level == 0) ? 11 : 10;
        const unsigned int nmask = (1u << nnb) - 1u;
        __syncthreads();
#pragma unroll
        for (int j = 0; j < 8; ++j) hist[t + 256 * j] = 0u;
        __syncthreads();
#pragma unroll
        for (int i = 0; i < 16; ++i) {
            const unsigned int u = k[i];
            if ((u >> (nshift + nnb)) == prefix)
                atomicAdd(&hist[(u >> nshift) & nmask], 1u);
        }
        shift = nshift;
        __syncthreads();
    }

    // compact from registers: definite members + threshold-bin candidates
    if (t == 0) { sc[3] = 0u; sc[4] = 0u; }
    __syncthreads();
#pragma unroll
    for (int i = 0; i < 16; ++i) {
        const unsigned int u = k[i];
        const unsigned int hp = (shift == 0) ? u : (u >> shift);
        if (hp < prefix) {
            outidx[atomicAdd(&sc[3], 1u)] = i * 256 + t;
        } else if (hp == prefix) {
            const unsigned int slot = atomicAdd(&sc[4], 1u);
            if (slot < 64u) { ckey[slot] = u; cidx[slot] = i * 256 + t; }
        }
    }
    __syncthreads();
    const int defcnt  = (int)sc[3];
    const int candcnt = min((int)sc[4], 64);

    // wave 0: exact (key, idx) lexicographic rank among candidates
    if (wv == 0) {
        const unsigned int k_l = (lane < candcnt) ? ckey[lane] : 0xFFFFFFFFu;
        const int          i_l = (lane < candcnt) ? cidx[lane] : 0x7FFFFFFF;
        int rk = 0;
        for (int j = 0; j < candcnt; ++j) {
            const unsigned int kj = __shfl(k_l, j);
            const int          ij = __shfl(i_l, j);
            if (kj < k_l || (kj == k_l && ij < i_l)) ++rk;
        }
        if (lane < candcnt && rk <= (int)rank) outidx[defcnt + rk] = i_l;
    }
    __syncthreads();
    if (t < KNN) nn[(size_t)bid * KNN + t] = outidx[t];
    if (t == 0) {
        pos_q[(size_t)bid * 3 + 0] = qv.x;
        pos_q[(size_t)bid * 3 + 1] = qv.y;
        pos_q[(size_t)bid * 3 + 2] = qv.z;
    }
}

// ---------------------------------------------------------------------------
// Kernel 2: fused gather + MLP via f16 MFMA 16x16x32 + max over K.
// (unchanged from round 3/4 — passed with absmax 0.031)
// ---------------------------------------------------------------------------
#define W1F_H 0
#define W2F_H 6144
#define XH_H  14336
#define SH_HALVES (XH_H + 4 * 3072)

__global__ __launch_bounds__(256) void mlp_kernel(
    const float* __restrict__ pos, const float* __restrict__ feat,
    const float* __restrict__ b1, const float* __restrict__ b2,
    const float* __restrict__ pos_q, const int* __restrict__ nn,
    const _Float16* __restrict__ wf, float* __restrict__ out)
{
    __shared__ _Float16 sh[SH_HALVES];
    const int t = threadIdx.x;
    const int w = t >> 6, lane = t & 63;
    const int col = lane & 15, quad = lane >> 4;
    const int qblk = blockIdx.x * 4;

    {
        const int4* src = (const int4*)wf;
        int4* dst = (int4*)sh;
#pragma unroll
        for (int r = 0; r < 7; ++r) dst[t + 256 * r] = src[t + 256 * r];
    }

    {
        const int r = t >> 1, h = t & 1;
        const int ql = r >> 5, kk = r & 31;
        const int q = qblk + ql, b = q >> 10;
        const int n = nn[(size_t)q * KNN + kk];
        const float* frow = feat + ((size_t)(b * NPTS + n)) * CIN;
        const float4* f4 = (const float4*)frow;
        const int mt = kk >> 4, lrow = kk & 15;
        const int base = XH_H + ql * 3072;
        if (h == 0) {
            float rel[3];
#pragma unroll
            for (int c = 0; c < 3; ++c)
                rel[c] = pos[(size_t)b * NPTS * 3 + n * 3 + c] - pos_q[(size_t)q * 3 + c];
            float fb[48];
#pragma unroll
            for (int ii = 0; ii < 12; ++ii) {
                const float4 v = f4[ii];
                fb[4*ii] = v.x; fb[4*ii+1] = v.y; fb[4*ii+2] = v.z; fb[4*ii+3] = v.w;
            }
#pragma unroll
            for (int cidx2 = 0; cidx2 < 6; ++cidx2) {
                half8 ph;
#pragma unroll
                for (int jj = 0; jj < 8; ++jj) {
                    const int c = cidx2 * 8 + jj;
                    ph[jj] = (_Float16)((c < 3) ? rel[c] : fb[c - 3]);
                }
                const int kc = cidx2 >> 2, qd = cidx2 & 3;
                *(half8*)&sh[base + ((kc * 2 + mt) * 64 + qd * 16 + lrow) * 8] = ph;
            }
        } else {
            float fb[20];
#pragma unroll
            for (int ii = 0; ii < 5; ++ii) {
                const float4 v = f4[11 + ii];
                fb[4*ii] = v.x; fb[4*ii+1] = v.y; fb[4*ii+2] = v.z; fb[4*ii+3] = v.w;
            }
#pragma unroll
            for (int cidx2 = 6; cidx2 < 12; ++cidx2) {
                half8 ph;
#pragma unroll
                for (int jj = 0; jj < 8; ++jj) {
                    const int c = cidx2 * 8 + jj;
                    ph[jj] = (_Float16)((c < 67) ? fb[c - 47] : 0.0f);
                }
                const int kc = cidx2 >> 2, qd = cidx2 & 3;
                *(half8*)&sh[base + ((kc * 2 + mt) * 64 + qd * 16 + lrow) * 8] = ph;
            }
        }
    }
    __syncthreads();

    const int q = qblk + w;
    const int wbase = XH_H + w * 3072;

    half8 af[3][2];
#pragma unroll
    for (int kc = 0; kc < 3; ++kc)
#pragma unroll
        for (int mt = 0; mt < 2; ++mt)
            af[kc][mt] = *(const half8*)&sh[wbase + ((kc * 2 + mt) * 64 + lane) * 8];

#pragma unroll
    for (int nt = 0; nt < 4; ++nt) {
        const float bv = b1[nt * 16 + col];
        floatx4 acc0 = {bv, bv, bv, bv}, acc1 = acc0;
#pragma unroll
        for (int kc = 0; kc < 3; ++kc) {
            const half8 bf = *(const half8*)&sh[W1F_H + ((kc * 4 + nt) * 64 + lane) * 8];
            acc0 = __builtin_amdgcn_mfma_f32_16x16x32_f16(af[kc][0], bf, acc0, 0, 0, 0);
            acc1 = __builtin_amdgcn_mfma_f32_16x16x32_f16(af[kc][1], bf, acc1, 0, 0, 0);
        }
        const int kc2 = nt >> 1;
        const int quad2 = (((nt & 1) * 16) + col) >> 3;
        const int j2 = col & 7;
#pragma unroll
        for (int mt = 0; mt < 2; ++mt) {
            const floatx4 a = mt ? acc1 : acc0;
#pragma unroll
            for (int reg = 0; reg < 4; ++reg) {
                const int row = quad * 4 + reg;
                sh[wbase + ((kc2 * 2 + mt) * 64 + quad2 * 16 + row) * 8 + j2] =
                    (_Float16)fmaxf(a[reg], 0.0f);
            }
        }
    }

    half8 a2[2][2];
#pragma unroll
    for (int kc2 = 0; kc2 < 2; ++kc2)
#pragma unroll
        for (int mt = 0; mt < 2; ++mt)
            a2[kc2][mt] = *(const half8*)&sh[wbase + ((kc2 * 2 + mt) * 64 + lane) * 8];

    float* oq = out + (size_t)q * H2D;
#pragma unroll
    for (int nt2 = 0; nt2 < 8; ++nt2) {
        const float bv = b2[nt2 * 16 + col];
        floatx4 acc0 = {bv, bv, bv, bv}, acc1 = acc0;
#pragma unroll
        for (int kc2 = 0; kc2 < 2; ++kc2) {
            const half8 bf = *(const half8*)&sh[W2F_H + ((kc2 * 8 + nt2) * 64 + lane) * 8];
            acc0 = __builtin_amdgcn_mfma_f32_16x16x32_f16(a2[kc2][0], bf, acc0, 0, 0, 0);
            acc1 = __builtin_amdgcn_mfma_f32_16x16x32_f16(a2[kc2][1], bf, acc1, 0, 0, 0);
        }
        float mm = fmaxf(fmaxf(fmaxf(acc0[0], acc0[1]), fmaxf(acc0[2], acc0[3])),
                         fmaxf(fmaxf(acc1[0], acc1[1]), fmaxf(acc1[2], acc1[3])));
        mm = fmaxf(mm, 0.0f);
        mm = fmaxf(mm, __shfl_xor(mm, 16));
        mm = fmaxf(mm, __shfl_xor(mm, 32));
        if (lane < 16) oq[nt2 * 16 + lane] = mm;
    }
}

extern "C" void kernel_launch(void* const* d_in, const int* in_sizes, int n_in,
                              void* d_out, int out_size, void* d_ws, size_t ws_size,
                              hipStream_t stream)
{
    const float* pos  = (const float*)d_in[0];
    const float* feat = (const float*)d_in[1];
    const float* W1   = (const float*)d_in[2];
    const float* b1   = (const float*)d_in[3];
    const float* W2   = (const float*)d_in[4];
    const float* b2   = (const float*)d_in[5];
    const int*   idx  = (const int*)d_in[6];   // int64 delivered as int32

    float* pos_q = (float*)d_out;
    float* out   = (float*)d_out + (size_t)BATCH * MQ * 3;
    int*      nn = (int*)d_ws;
    _Float16* wf = (_Float16*)((char*)d_ws + WS_NN_BYTES);
    float4*   p4 = (float4*)((char*)d_ws + WS_P4_OFF);

    const int prep_threads = 1792 + BATCH * NPTS;
    wprep_kernel<<<(prep_threads + 255) / 256, 256, 0, stream>>>(W1, W2, pos, wf, p4);
    knn_kernel<<<BATCH * MQ, 256, 0, stream>>>(p4, idx, pos_q, nn);
    mlp_kernel<<<BATCH * MQ / 4, 256, 0, stream>>>(pos, feat, b1, b2,
                                                   pos_q, nn, wf, out);
}

// Round 6
// 196.423 us; speedup vs baseline: 4.9557x; 1.0430x over previous
//
#include <hip/hip_runtime.h>

#define NPTS  4096
#define MQ    1024
#define BATCH 16
#define KNN   32
#define CIN   64
#define H1D   64
#define H2D   128

typedef _Float16 half8 __attribute__((ext_vector_type(8)));
typedef float    floatx4 __attribute__((ext_vector_type(4)));

// ws layout: nn [2 MB] | W1f+W2f fragments [28 KB] | pos4 [1 MB]
#define WS_NN_BYTES ((size_t)BATCH * MQ * KNN * 4)
#define W1F_HALVES  (3 * 4 * 64 * 8)
#define W2F_HALVES  (2 * 8 * 64 * 8)
#define WS_P4_OFF   (WS_NN_BYTES + (W1F_HALVES + W2F_HALVES) * 2)

// ---------------------------------------------------------------------------
// Kernel 0: pack W1/W2 into f16 MFMA B-fragment layout + pack pos into
// float4 {x,y,z,|p|^2}  (|p|^2 with the exact reference association).
// ---------------------------------------------------------------------------
__global__ __launch_bounds__(256) void wprep_kernel(
    const float* __restrict__ W1, const float* __restrict__ W2,
    const float* __restrict__ pos,
    _Float16* __restrict__ wout, float4* __restrict__ pos4)
{
    const int gid = blockIdx.x * 256 + threadIdx.x;
    if (gid < 768) {                                 // W1 fragments
        const int s = gid;
        const int kc = s >> 8, nt = (s >> 6) & 3, lane = s & 63;
        const int col = lane & 15, quad = lane >> 4;
        half8 ph;
#pragma unroll
        for (int j = 0; j < 8; ++j) {
            const int k = kc * 32 + quad * 8 + j;
            ph[j] = (k < 67) ? (_Float16)W1[k * H1D + nt * 16 + col] : (_Float16)0.0f;
        }
        *(half8*)(wout + (size_t)s * 8) = ph;
    } else if (gid < 1792) {                         // W2 fragments
        const int s2 = gid - 768;
        const int kc2 = s2 >> 9, nt2 = (s2 >> 6) & 7, lane = s2 & 63;
        const int col = lane & 15, quad = lane >> 4;
        half8 ph;
#pragma unroll
        for (int j = 0; j < 8; ++j) {
            const int k = kc2 * 32 + quad * 8 + j;
            ph[j] = (_Float16)W2[k * H2D + nt2 * 16 + col];
        }
        *(half8*)(wout + (size_t)W1F_HALVES + (size_t)s2 * 8) = ph;
    } else {                                         // pos4 for all B*N points
        const int p = gid - 1792;
        if (p < BATCH * NPTS) {
            const float px = pos[p * 3 + 0], py = pos[p * 3 + 1], pz = pos[p * 3 + 2];
            float4 v;
            v.x = px; v.y = py; v.z = pz;
            v.w = __fadd_rn(__fadd_rn(__fmul_rn(px, px), __fmul_rn(py, py)),
                            __fmul_rn(pz, pz));
            pos4[p] = v;
        }
    }
}

// ---------------------------------------------------------------------------
// Kernel 1: exact KNN. Keys (monotone-mapped fp32 d2, bitwise-matching the
// numpy reference — verified absmax 0.0 in r2) in 16 VGPRs/thread.
// r6 change: preload all 16 float4 into registers so the 16 loads are in
// flight simultaneously (r5 had VGPR=36 -> one load at a time, latency-bound).
// ---------------------------------------------------------------------------
__global__ __launch_bounds__(256, 4) void knn_kernel(
    const float4* __restrict__ pos4, const int* __restrict__ idx,
    float* __restrict__ pos_q, int* __restrict__ nn)
{
    const int bid = blockIdx.x;
    const int b   = bid >> 10;
    const int m   = bid & (MQ - 1);
    const int t   = threadIdx.x;
    const int wv  = t >> 6, lane = t & 63;

    __shared__ unsigned int hist[2048];     // 8 KB
    __shared__ unsigned int wsum[4];
    __shared__ unsigned int sc[8];
    __shared__ unsigned int ckey[64];
    __shared__ int          cidx[64];
    __shared__ int          outidx[KNN];

    const float4* pb4 = pos4 + (size_t)b * NPTS;
    const int qn = idx[(size_t)b * MQ + m];
    const float4 qv = pb4[qn];
    const float qq = qv.w;

#pragma unroll
    for (int j = 0; j < 8; ++j) hist[t + 256 * j] = 0u;
    __syncthreads();

    // preload all 16 points -> 16 loads in flight, one wait
    float4 p[16];
#pragma unroll
    for (int i = 0; i < 16; ++i) p[i] = pb4[i * 256 + t];

    unsigned int k[16];
#pragma unroll
    for (int i = 0; i < 16; ++i) {
        const float qp = __fadd_rn(__fadd_rn(__fmul_rn(qv.x, p[i].x), __fmul_rn(qv.y, p[i].y)),
                                   __fmul_rn(qv.z, p[i].z));
        const float d2 = __fsub_rn(__fadd_rn(qq, p[i].w), __fmul_rn(2.0f, qp));
        unsigned int u = __float_as_uint(d2);
        u = (u & 0x80000000u) ? ~u : (u | 0x80000000u);
        k[i] = u;
        atomicAdd(&hist[u >> 21], 1u);
    }
    __syncthreads();

    unsigned int prefix = 0u, rank = KNN - 1;
    int shift = 21, bcnt;
    for (int level = 0; level < 3; ++level) {
        const int nb = (level < 2) ? 11 : 10;
        const int g  = (1 << nb) >> 8;
        unsigned int cnt[8];
        unsigned int s = 0;
        for (int j = 0; j < g; ++j) { cnt[j] = hist[t * g + j]; s += cnt[j]; }
        unsigned int v = s;
#pragma unroll
        for (int off = 1; off < 64; off <<= 1) {
            const unsigned int o = __shfl_up(v, off);
            if (lane >= off) v += o;
        }
        if (lane == 63) wsum[wv] = v;
        __syncthreads();
        unsigned int woff = 0;
        for (int i = 0; i < wv; ++i) woff += wsum[i];
        const unsigned int incl = woff + v, excl = incl - s;
        if (rank >= excl && rank < incl) {
            unsigned int e = excl;
            for (int j = 0; j < g; ++j) {
                if (rank < e + cnt[j]) {
                    sc[0] = (prefix << nb) | (unsigned int)(t * g + j);
                    sc[1] = rank - e;
                    sc[2] = cnt[j];
                    break;
                }
                e += cnt[j];
            }
        }
        __syncthreads();
        prefix = sc[0];
        rank   = sc[1];
        bcnt   = (int)sc[2];
        if (level == 2 || bcnt <= 64) break;

        const int nshift = (level == 0) ? 10 : 0;
        const int nnb    = (level == 0) ? 11 : 10;
        const unsigned int nmask = (1u << nnb) - 1u;
        __syncthreads();
#pragma unroll
        for (int j = 0; j < 8; ++j) hist[t + 256 * j] = 0u;
        __syncthreads();
#pragma unroll
        for (int i = 0; i < 16; ++i) {
            const unsigned int u = k[i];
            if ((u >> (nshift + nnb)) == prefix)
                atomicAdd(&hist[(u >> nshift) & nmask], 1u);
        }
        shift = nshift;
        __syncthreads();
    }

    if (t == 0) { sc[3] = 0u; sc[4] = 0u; }
    __syncthreads();
#pragma unroll
    for (int i = 0; i < 16; ++i) {
        const unsigned int u = k[i];
        const unsigned int hp = (shift == 0) ? u : (u >> shift);
        if (hp < prefix) {
            outidx[atomicAdd(&sc[3], 1u)] = i * 256 + t;
        } else if (hp == prefix) {
            const unsigned int slot = atomicAdd(&sc[4], 1u);
            if (slot < 64u) { ckey[slot] = u; cidx[slot] = i * 256 + t; }
        }
    }
    __syncthreads();
    const int defcnt  = (int)sc[3];
    const int candcnt = min((int)sc[4], 64);

    if (wv == 0) {
        const unsigned int k_l = (lane < candcnt) ? ckey[lane] : 0xFFFFFFFFu;
        const int          i_l = (lane < candcnt) ? cidx[lane] : 0x7FFFFFFF;
        int rk = 0;
        for (int j = 0; j < candcnt; ++j) {
            const unsigned int kj = __shfl(k_l, j);
            const int          ij = __shfl(i_l, j);
            if (kj < k_l || (kj == k_l && ij < i_l)) ++rk;
        }
        if (lane < candcnt && rk <= (int)rank) outidx[defcnt + rk] = i_l;
    }
    __syncthreads();
    if (t < KNN) nn[(size_t)bid * KNN + t] = outidx[t];
    if (t == 0) {
        pos_q[(size_t)bid * 3 + 0] = qv.x;
        pos_q[(size_t)bid * 3 + 1] = qv.y;
        pos_q[(size_t)bid * 3 + 2] = qv.z;
    }
}

// ---------------------------------------------------------------------------
// Kernel 2: fused gather + MLP via f16 MFMA 16x16x32 + max over K.
// r6 restructure: weights live in per-wave VGPRs (not LDS) -> zero barriers,
// LDS 52->24 KB (wave-private X/H1 fragment region only). Gather uses packed
// pos4 + preloads the 12 feature float4s for ILP. Fragment math identical to
// the r3-verified kernel (absmax 0.031).
// ---------------------------------------------------------------------------
__global__ __launch_bounds__(256, 4) void mlp_kernel(
    const float4* __restrict__ pos4, const float* __restrict__ feat,
    const float* __restrict__ b1, const float* __restrict__ b2,
    const float* __restrict__ pos_q, const int* __restrict__ nn,
    const _Float16* __restrict__ wf, float* __restrict__ out)
{
    __shared__ _Float16 sh[4 * 3072];       // 24 KB, wave-private 6 KB regions
    const int t = threadIdx.x;
    const int w = t >> 6, lane = t & 63;
    const int col = lane & 15, quad = lane >> 4;
    const int q = blockIdx.x * 4 + w;       // wave-uniform query id
    const int b = q >> 10;
    const int wbase = w * 3072;

    // gather + pack X A-frags (2 threads per neighbor row; rows of query w
    // are handled entirely by wave w -> wave-private, no barrier needed)
    {
        const int r = t >> 1, h = t & 1;
        const int kk = r & 31;
        const int n = nn[(size_t)q * KNN + kk];
        const float4 pv = pos4[(size_t)b * NPTS + n];
        const float4* f4 = (const float4*)(feat + ((size_t)b * NPTS + n) * CIN);
        const int mt = kk >> 4, lrow = kk & 15;
        if (h == 0) {                        // cols 0..47: rel(3) + feat[0..44]
            float4 ff[12];
#pragma unroll
            for (int ii = 0; ii < 12; ++ii) ff[ii] = f4[ii];
            float rel[3];
            rel[0] = pv.x - pos_q[(size_t)q * 3 + 0];
            rel[1] = pv.y - pos_q[(size_t)q * 3 + 1];
            rel[2] = pv.z - pos_q[(size_t)q * 3 + 2];
#pragma unroll
            for (int ci = 0; ci < 6; ++ci) {
                half8 ph;
#pragma unroll
                for (int jj = 0; jj < 8; ++jj) {
                    const int c = ci * 8 + jj;
                    float v;
                    if (c < 3) v = rel[c];
                    else {
                        const int fc = c - 3;
                        const float4 vv = ff[fc >> 2];
                        v = ((fc & 3) == 0) ? vv.x : ((fc & 3) == 1) ? vv.y
                          : ((fc & 3) == 2) ? vv.z : vv.w;
                    }
                    ph[jj] = (_Float16)v;
                }
                const int kc = ci >> 2, qd = ci & 3;
                *(half8*)&sh[wbase + ((kc * 2 + mt) * 64 + qd * 16 + lrow) * 8] = ph;
            }
        } else {                             // cols 48..95: feat[45..63] + pad
            float4 ff[5];
#pragma unroll
            for (int ii = 0; ii < 5; ++ii) ff[ii] = f4[11 + ii];
#pragma unroll
            for (int ci = 6; ci < 12; ++ci) {
                half8 ph;
#pragma unroll
                for (int jj = 0; jj < 8; ++jj) {
                    const int c = ci * 8 + jj;
                    float v = 0.0f;
                    if (c < 67) {
                        const int fc = c - 3;            // 45..63
                        const float4 vv = ff[(fc >> 2) - 11];
                        v = ((fc & 3) == 0) ? vv.x : ((fc & 3) == 1) ? vv.y
                          : ((fc & 3) == 2) ? vv.z : vv.w;
                    }
                    ph[jj] = (_Float16)v;
                }
                const int kc = ci >> 2, qd = ci & 3;
                *(half8*)&sh[wbase + ((kc * 2 + mt) * 64 + qd * 16 + lrow) * 8] = ph;
            }
        }
    }
    // no __syncthreads(): all LDS traffic below is same-wave, DS pipe in-order

    // layer 1: A-frags from LDS, W1 B-frags from global into VGPRs
    half8 af[3][2];
#pragma unroll
    for (int kc = 0; kc < 3; ++kc)
#pragma unroll
        for (int mt = 0; mt < 2; ++mt)
            af[kc][mt] = *(const half8*)&sh[wbase + ((kc * 2 + mt) * 64 + lane) * 8];

    half8 w1f[3][4];
#pragma unroll
    for (int kc = 0; kc < 3; ++kc)
#pragma unroll
        for (int nt = 0; nt < 4; ++nt)
            w1f[kc][nt] = *(const half8*)(wf + (size_t)((kc * 4 + nt) * 64 + lane) * 8);

#pragma unroll
    for (int nt = 0; nt < 4; ++nt) {
        const float bv = b1[nt * 16 + col];
        floatx4 acc0 = {bv, bv, bv, bv}, acc1 = acc0;
#pragma unroll
        for (int kc = 0; kc < 3; ++kc) {
            acc0 = __builtin_amdgcn_mfma_f32_16x16x32_f16(af[kc][0], w1f[kc][nt], acc0, 0, 0, 0);
            acc1 = __builtin_amdgcn_mfma_f32_16x16x32_f16(af[kc][1], w1f[kc][nt], acc1, 0, 0, 0);
        }
        const int kc2 = nt >> 1;
        const int quad2 = (((nt & 1) * 16) + col) >> 3;
        const int j2 = col & 7;
#pragma unroll
        for (int mt = 0; mt < 2; ++mt) {
            const floatx4 a = mt ? acc1 : acc0;
#pragma unroll
            for (int reg = 0; reg < 4; ++reg) {
                const int row = quad * 4 + reg;
                sh[wbase + ((kc2 * 2 + mt) * 64 + quad2 * 16 + row) * 8 + j2] =
                    (_Float16)fmaxf(a[reg], 0.0f);
            }
        }
    }

    // layer 2 + max over K
    half8 a2[2][2];
#pragma unroll
    for (int kc2 = 0; kc2 < 2; ++kc2)
#pragma unroll
        for (int mt = 0; mt < 2; ++mt)
            a2[kc2][mt] = *(const half8*)&sh[wbase + ((kc2 * 2 + mt) * 64 + lane) * 8];

    half8 w2f[2][8];
#pragma unroll
    for (int kc2 = 0; kc2 < 2; ++kc2)
#pragma unroll
        for (int nt2 = 0; nt2 < 8; ++nt2)
            w2f[kc2][nt2] = *(const half8*)(wf + (size_t)W1F_HALVES
                                            + (size_t)((kc2 * 8 + nt2) * 64 + lane) * 8);

    float* oq = out + (size_t)q * H2D;
#pragma unroll
    for (int nt2 = 0; nt2 < 8; ++nt2) {
        const float bv = b2[nt2 * 16 + col];
        floatx4 acc0 = {bv, bv, bv, bv}, acc1 = acc0;
#pragma unroll
        for (int kc2 = 0; kc2 < 2; ++kc2) {
            acc0 = __builtin_amdgcn_mfma_f32_16x16x32_f16(a2[kc2][0], w2f[kc2][nt2], acc0, 0, 0, 0);
            acc1 = __builtin_amdgcn_mfma_f32_16x16x32_f16(a2[kc2][1], w2f[kc2][nt2], acc1, 0, 0, 0);
        }
        float mm = fmaxf(fmaxf(fmaxf(acc0[0], acc0[1]), fmaxf(acc0[2], acc0[3])),
                         fmaxf(fmaxf(acc1[0], acc1[1]), fmaxf(acc1[2], acc1[3])));
        mm = fmaxf(mm, 0.0f);
        mm = fmaxf(mm, __shfl_xor(mm, 16));
        mm = fmaxf(mm, __shfl_xor(mm, 32));
        if (lane < 16) oq[nt2 * 16 + lane] = mm;
    }
}

extern "C" void kernel_launch(void* const* d_in, const int* in_sizes, int n_in,
                              void* d_out, int out_size, void* d_ws, size_t ws_size,
                              hipStream_t stream)
{
    const float* pos  = (const float*)d_in[0];
    const float* feat = (const float*)d_in[1];
    const float* W1   = (const float*)d_in[2];
    const float* b1   = (const float*)d_in[3];
    const float* W2   = (const float*)d_in[4];
    const float* b2   = (const float*)d_in[5];
    const int*   idx  = (const int*)d_in[6];   // int64 delivered as int32

    float* pos_q = (float*)d_out;
    float* out   = (float*)d_out + (size_t)BATCH * MQ * 3;
    int*      nn = (int*)d_ws;
    _Float16* wf = (_Float16*)((char*)d_ws + WS_NN_BYTES);
    float4*   p4 = (float4*)((char*)d_ws + WS_P4_OFF);

    const int prep_threads = 1792 + BATCH * NPTS;
    wprep_kernel<<<(prep_threads + 255) / 256, 256, 0, stream>>>(W1, W2, pos, wf, p4);
    knn_kernel<<<BATCH * MQ, 256, 0, stream>>>(p4, idx, pos_q, nn);
    mlp_kernel<<<BATCH * MQ / 4, 256, 0, stream>>>(p4, feat, b1, b2,
                                                   pos_q, nn, wf, out);
}